// Round 1
// baseline (8262.991 us; speedup 1.0000x reference)
//
#include <hip/hip_runtime.h>
#include <hip/hip_bf16.h>

// ---- model dims ----
#define Dm    768
#define Hh    12
#define Ll    2
#define Ee    8
#define Vv    50257
#define Tt    512
#define Bbatch 4
#define TIi   49
#define IMGF  2048
#define FFf   3072
#define NTOK  2048      // B*T
#define NIMG  196       // B*TI
#define HD    64        // head dim
#define SLOTS 4608      // max padded (token,expert) pairs: 4096 + 8*63 rounded
#define MAXTILES 72     // max sum ceil(cnt_e/64) = 8 + 4096/64

__device__ __forceinline__ float gelu_f(float x) {
  const float c0 = 0.7978845608028654f;
  float t = tanhf(c0 * (x + 0.044715f * x * x * x));
  return 0.5f * x * (1.0f + t);
}

// =====================================================================
// Generic NT GEMM: Y[m,n] = act( scale * sum_k X[m,k]*W[n,k] + bias[n] ) + R[m%rmod,n]
// Both X and W reduced along their contiguous dim. Batched via grid.z with
// (b,h) stride decomposition: offset = (z/nH)*b_stride + (z%nH)*h_stride.
// Requires K % 16 == 0, ld* % 4 == 0, 16B-aligned bases.
// =====================================================================
__global__ void __launch_bounds__(256)
k_gemm_nt(const float* __restrict__ X, int ldx, long long bxb, long long bxh,
          const float* __restrict__ W, int ldw, long long bwb, long long bwh,
          const float* __restrict__ bias,
          const float* R, int rmod,
          float* Y, int ldy, long long byb, long long byh,
          int M, int N, int K, int nH, int act, float scale)
{
  int z = blockIdx.z;
  int zb = z / nH, zh = z - zb * nH;
  X += (long long)zb * bxb + (long long)zh * bxh;
  W += (long long)zb * bwb + (long long)zh * bwh;
  Y += (long long)zb * byb + (long long)zh * byh;
  __shared__ float Xs[16][65];
  __shared__ float Ws[16][65];
  const int tid = threadIdx.x;
  const int tx = tid & 15, ty = tid >> 4;
  const int lrow = tid >> 2, lk4 = (tid & 3) << 2;
  const int row0 = blockIdx.y << 6, col0 = blockIdx.x << 6;
  const bool xok = (row0 + lrow) < M;
  const bool wok = (col0 + lrow) < N;
  const float* xp = X + (long long)(row0 + lrow) * ldx + lk4;
  const float* wp = W + (long long)(col0 + lrow) * ldw + lk4;
  float acc[4][4] = {};
  for (int k0 = 0; k0 < K; k0 += 16) {
    float4 xv = make_float4(0.f, 0.f, 0.f, 0.f);
    if (xok) xv = *(const float4*)(xp + k0);
    Xs[lk4 + 0][lrow] = xv.x; Xs[lk4 + 1][lrow] = xv.y;
    Xs[lk4 + 2][lrow] = xv.z; Xs[lk4 + 3][lrow] = xv.w;
    float4 wv = make_float4(0.f, 0.f, 0.f, 0.f);
    if (wok) wv = *(const float4*)(wp + k0);
    Ws[lk4 + 0][lrow] = wv.x; Ws[lk4 + 1][lrow] = wv.y;
    Ws[lk4 + 2][lrow] = wv.z; Ws[lk4 + 3][lrow] = wv.w;
    __syncthreads();
#pragma unroll
    for (int kk = 0; kk < 16; ++kk) {
      float a[4], bv[4];
#pragma unroll
      for (int i = 0; i < 4; ++i) a[i] = Xs[kk][(ty << 2) + i];
#pragma unroll
      for (int j = 0; j < 4; ++j) bv[j] = Ws[kk][(tx << 2) + j];
#pragma unroll
      for (int i = 0; i < 4; ++i)
#pragma unroll
        for (int j = 0; j < 4; ++j) acc[i][j] += a[i] * bv[j];
    }
    __syncthreads();
  }
#pragma unroll
  for (int i = 0; i < 4; ++i) {
    int r = row0 + (ty << 2) + i;
    if (r >= M) continue;
#pragma unroll
    for (int j = 0; j < 4; ++j) {
      int c = col0 + (tx << 2) + j;
      if (c >= N) continue;
      float v = acc[i][j] * scale;
      if (bias) v += bias[c];
      if (act) v = gelu_f(v);
      if (R) v += R[(long long)(r % rmod) * ldy + c];
      Y[(long long)r * ldy + c] = v;
    }
  }
}

// =====================================================================
// Generic NN GEMM (for A @ V): Y[m,n] = sum_k X[m,k]*W[k,n]
// Requires ldx >= roundup(K,16) with the pad region zero-initialized
// (softmax zeroes it). W loads are k-guarded.
// =====================================================================
__global__ void __launch_bounds__(256)
k_gemm_nn(const float* __restrict__ X, int ldx, long long bxb, long long bxh,
          const float* __restrict__ W, int ldw, long long bwb, long long bwh,
          float* __restrict__ Y, int ldy, long long byb, long long byh,
          int M, int N, int K, int nH)
{
  int z = blockIdx.z;
  int zb = z / nH, zh = z - zb * nH;
  X += (long long)zb * bxb + (long long)zh * bxh;
  W += (long long)zb * bwb + (long long)zh * bwh;
  Y += (long long)zb * byb + (long long)zh * byh;
  __shared__ float Xs[16][65];
  __shared__ float Ws[16][65];
  const int tid = threadIdx.x;
  const int tx = tid & 15, ty = tid >> 4;
  const int lrow = tid >> 2, lk4 = (tid & 3) << 2;
  const int wk = tid >> 4, wo4 = (tid & 15) << 2;
  const int row0 = blockIdx.y << 6, col0 = blockIdx.x << 6;
  const bool xok = (row0 + lrow) < M;
  const int Kpad = (K + 15) & ~15;
  float acc[4][4] = {};
  for (int k0 = 0; k0 < Kpad; k0 += 16) {
    float4 xv = make_float4(0.f, 0.f, 0.f, 0.f);
    if (xok) xv = *(const float4*)(X + (long long)(row0 + lrow) * ldx + k0 + lk4);
    Xs[lk4 + 0][lrow] = xv.x; Xs[lk4 + 1][lrow] = xv.y;
    Xs[lk4 + 2][lrow] = xv.z; Xs[lk4 + 3][lrow] = xv.w;
    float4 wv = make_float4(0.f, 0.f, 0.f, 0.f);
    if ((k0 + wk) < K && (col0 + wo4) < N)
      wv = *(const float4*)(W + (long long)(k0 + wk) * ldw + col0 + wo4);
    Ws[wk][wo4 + 0] = wv.x; Ws[wk][wo4 + 1] = wv.y;
    Ws[wk][wo4 + 2] = wv.z; Ws[wk][wo4 + 3] = wv.w;
    __syncthreads();
#pragma unroll
    for (int kk = 0; kk < 16; ++kk) {
      float a[4], bv[4];
#pragma unroll
      for (int i = 0; i < 4; ++i) a[i] = Xs[kk][(ty << 2) + i];
#pragma unroll
      for (int j = 0; j < 4; ++j) bv[j] = Ws[kk][(tx << 2) + j];
#pragma unroll
      for (int i = 0; i < 4; ++i)
#pragma unroll
        for (int j = 0; j < 4; ++j) acc[i][j] += a[i] * bv[j];
    }
    __syncthreads();
  }
#pragma unroll
  for (int i = 0; i < 4; ++i) {
    int r = row0 + (ty << 2) + i;
    if (r >= M) continue;
#pragma unroll
    for (int j = 0; j < 4; ++j) {
      int c = col0 + (tx << 2) + j;
      if (c >= N) continue;
      Y[(long long)r * ldy + c] = acc[i][j];
    }
  }
}

// ---- token embedding: x[b,t,:] = wte[idx[b,t],:] + wpe[t,:] ----
__global__ void k_embed(const int* __restrict__ idx, const float* __restrict__ wte,
                        const float* __restrict__ wpe, float* __restrict__ x)
{
  int bt = blockIdx.x;
  int tt = bt % Tt;
  int tok = idx[bt];
  int t = threadIdx.x;
  float* xr = x + (long long)bt * Dm;
  const float* wr = wte + (long long)tok * Dm;
  const float* pr = wpe + (long long)tt * Dm;
  xr[t]       = wr[t]       + pr[t];
  xr[t + 256] = wr[t + 256] + pr[t + 256];
  xr[t + 512] = wr[t + 512] + pr[t + 512];
}

// ---- LayerNorm over last dim (768), one block (256 thr) per row ----
__global__ void k_ln(const float* __restrict__ X, const float* __restrict__ s,
                     const float* __restrict__ b, float* __restrict__ Yo)
{
  int row = blockIdx.x;
  int t = threadIdx.x;
  const float* xr = X + (long long)row * Dm;
  float v0 = xr[t], v1 = xr[t + 256], v2 = xr[t + 512];
  float sum = v0 + v1 + v2;
  float sq = v0 * v0 + v1 * v1 + v2 * v2;
#pragma unroll
  for (int o = 32; o; o >>= 1) { sum += __shfl_xor(sum, o, 64); sq += __shfl_xor(sq, o, 64); }
  __shared__ float sS[4], sQ[4];
  if ((t & 63) == 0) { sS[t >> 6] = sum; sQ[t >> 6] = sq; }
  __syncthreads();
  sum = sS[0] + sS[1] + sS[2] + sS[3];
  sq  = sQ[0] + sQ[1] + sQ[2] + sQ[3];
  float m = sum * (1.f / 768.f);
  float inv = rsqrtf(sq * (1.f / 768.f) - m * m + 1e-5f);
  float* yr = Yo + (long long)row * Dm;
  yr[t]       = (v0 - m) * inv * s[t]       + b[t];
  yr[t + 256] = (v1 - m) * inv * s[t + 256] + b[t + 256];
  yr[t + 512] = (v2 - m) * inv * s[t + 512] + b[t + 512];
}

// ---- row softmax, one wave per row; zeroes [limit, ld) so NN-GEMM can
//      read the full padded row (also implements the causal mask) ----
__global__ void k_softmax(float* __restrict__ S, int Tq, int Tk, int ld, int causal)
{
  int q = blockIdx.x;
  float* row = S + ((long long)blockIdx.y * Tq + q) * ld;
  int lim = causal ? (q + 1) : Tk;
  int lane = threadIdx.x;
  float mx = -1e30f;
  for (int j = lane; j < lim; j += 64) mx = fmaxf(mx, row[j]);
#pragma unroll
  for (int o = 32; o; o >>= 1) mx = fmaxf(mx, __shfl_xor(mx, o, 64));
  float sum = 0.f;
  for (int j = lane; j < lim; j += 64) { float e = expf(row[j] - mx); row[j] = e; sum += e; }
#pragma unroll
  for (int o = 32; o; o >>= 1) sum += __shfl_xor(sum, o, 64);
  float inv = 1.f / sum;
  for (int j = lane; j < lim; j += 64) row[j] *= inv;
  for (int j = lim + lane; j < ld; j += 64) row[j] = 0.f;
}

// ---- MoE gate: sigmoid(x@gw^T+gb), top-2 (first-occurrence ties), counts ----
__global__ void k_gate(const float* __restrict__ Xln, const float* __restrict__ gw,
                       const float* __restrict__ gb, int* __restrict__ eidx,
                       float* __restrict__ ecw, int* __restrict__ counts)
{
  int n = blockIdx.x;
  int lane = threadIdx.x;
  const float* xr = Xln + (long long)n * Dm;
  float g[Ee];
#pragma unroll
  for (int e = 0; e < Ee; ++e) {
    float p = 0.f;
    for (int d = lane; d < Dm; d += 64) p += xr[d] * gw[e * Dm + d];
#pragma unroll
    for (int o = 32; o; o >>= 1) p += __shfl_xor(p, o, 64);
    g[e] = p;
  }
  if (lane == 0) {
    float gs[Ee];
#pragma unroll
    for (int e = 0; e < Ee; ++e) gs[e] = 1.f / (1.f + expf(-(g[e] + gb[e])));
    int i0 = 0; float v0 = gs[0];
#pragma unroll
    for (int e = 1; e < Ee; ++e) if (gs[e] > v0) { v0 = gs[e]; i0 = e; }
    int i1 = -1; float v1 = -1e30f;
#pragma unroll
    for (int e = 0; e < Ee; ++e) { if (e == i0) continue; if (gs[e] > v1) { v1 = gs[e]; i1 = e; } }
    eidx[2 * n] = i0; ecw[2 * n] = v0;
    eidx[2 * n + 1] = i1; ecw[2 * n + 1] = v1;
    atomicAdd(&counts[i0], 1);
    atomicAdd(&counts[i1], 1);
  }
}

// ---- scan: 64-padded per-expert offsets + row-tile table; zero cursors ----
__global__ void k_scan(const int* __restrict__ counts, int* __restrict__ offs,
                       int* __restrict__ cursor, int* __restrict__ te,
                       int* __restrict__ tr0, int* __restrict__ trn, int* __restrict__ ntl)
{
  if (threadIdx.x == 0 && blockIdx.x == 0) {
    int o = 0, nt = 0;
    for (int e = 0; e < Ee; ++e) {
      offs[e] = o;
      int c = counts[e];
      int pad = (c + 63) & ~63;
      for (int r = 0; r < pad; r += 64) {
        te[nt] = e; tr0[nt] = o + r;
        int rem = c - r; trn[nt] = rem < 64 ? rem : 64;
        nt++;
      }
      o += pad;
      cursor[e] = 0;
    }
    *ntl = nt;
  }
}

// ---- scatter pairs into per-expert slots ----
__global__ void k_scatter(const int* __restrict__ eidx, const int* __restrict__ offs,
                          int* __restrict__ cursor, int* __restrict__ stok, int* __restrict__ sof)
{
  int p = blockIdx.x * 256 + threadIdx.x;
  if (p >= 2 * NTOK) return;
  int e = eidx[p];
  int s = offs[e] + atomicAdd(&cursor[e], 1);
  stok[s] = p >> 1;
  sof[p] = s;
}

// ---- MoE GEMM1: Hm[slot, f] = gelu( x[token(slot)] . w1[e,f,:] + b1[e,f] ) ----
__global__ void __launch_bounds__(256)
k_moe_gemm1(const float* __restrict__ Xln, const float* __restrict__ W1,
            const float* __restrict__ B1,
            const int* __restrict__ te, const int* __restrict__ tr0,
            const int* __restrict__ trn, const int* __restrict__ ntl,
            const int* __restrict__ stok, float* __restrict__ Hm)
{
  int tile = blockIdx.y;
  if (tile >= *ntl) return;
  int e = te[tile], row0 = tr0[tile], nrows = trn[tile];
  const float* W = W1 + (size_t)e * FFf * Dm;
  const float* bias = B1 + (size_t)e * FFf;
  __shared__ float Xs[16][65];
  __shared__ float Ws[16][65];
  const int tid = threadIdx.x;
  const int tx = tid & 15, ty = tid >> 4;
  const int lrow = tid >> 2, lk4 = (tid & 3) << 2;
  const int col0 = blockIdx.x << 6;
  int gt = (lrow < nrows) ? stok[row0 + lrow] : -1;
  const float* xrow = Xln + (size_t)(gt < 0 ? 0 : gt) * Dm;
  const float* wp = W + (size_t)(col0 + lrow) * Dm + lk4;
  float acc[4][4] = {};
  for (int k0 = 0; k0 < Dm; k0 += 16) {
    float4 xv = make_float4(0.f, 0.f, 0.f, 0.f);
    if (gt >= 0) xv = *(const float4*)(xrow + k0 + lk4);
    Xs[lk4 + 0][lrow] = xv.x; Xs[lk4 + 1][lrow] = xv.y;
    Xs[lk4 + 2][lrow] = xv.z; Xs[lk4 + 3][lrow] = xv.w;
    float4 wv = *(const float4*)(wp + k0);
    Ws[lk4 + 0][lrow] = wv.x; Ws[lk4 + 1][lrow] = wv.y;
    Ws[lk4 + 2][lrow] = wv.z; Ws[lk4 + 3][lrow] = wv.w;
    __syncthreads();
#pragma unroll
    for (int kk = 0; kk < 16; ++kk) {
      float a[4], bv[4];
#pragma unroll
      for (int i = 0; i < 4; ++i) a[i] = Xs[kk][(ty << 2) + i];
#pragma unroll
      for (int j = 0; j < 4; ++j) bv[j] = Ws[kk][(tx << 2) + j];
#pragma unroll
      for (int i = 0; i < 4; ++i)
#pragma unroll
        for (int j = 0; j < 4; ++j) acc[i][j] += a[i] * bv[j];
    }
    __syncthreads();
  }
#pragma unroll
  for (int i = 0; i < 4; ++i) {
    int rl = (ty << 2) + i;
#pragma unroll
    for (int j = 0; j < 4; ++j) {
      int c = col0 + (tx << 2) + j;
      float v = (rl < nrows) ? gelu_f(acc[i][j] + bias[c]) : 0.f;
      Hm[(size_t)(row0 + rl) * FFf + c] = v;
    }
  }
}

// ---- MoE GEMM2: pb[slot, d] = Hm[slot,:] . w2[e,d,:] ----
__global__ void __launch_bounds__(256)
k_moe_gemm2(const float* __restrict__ Hm, const float* __restrict__ W2,
            const int* __restrict__ te, const int* __restrict__ tr0,
            const int* __restrict__ ntl, float* __restrict__ pb)
{
  int tile = blockIdx.y;
  if (tile >= *ntl) return;
  int e = te[tile], row0 = tr0[tile];
  const float* W = W2 + (size_t)e * Dm * FFf;
  __shared__ float Xs[16][65];
  __shared__ float Ws[16][65];
  const int tid = threadIdx.x;
  const int tx = tid & 15, ty = tid >> 4;
  const int lrow = tid >> 2, lk4 = (tid & 3) << 2;
  const int col0 = blockIdx.x << 6;
  const float* xp = Hm + (size_t)(row0 + lrow) * FFf + lk4;
  const float* wp = W + (size_t)(col0 + lrow) * FFf + lk4;
  float acc[4][4] = {};
  for (int k0 = 0; k0 < FFf; k0 += 16) {
    float4 xv = *(const float4*)(xp + k0);
    Xs[lk4 + 0][lrow] = xv.x; Xs[lk4 + 1][lrow] = xv.y;
    Xs[lk4 + 2][lrow] = xv.z; Xs[lk4 + 3][lrow] = xv.w;
    float4 wv = *(const float4*)(wp + k0);
    Ws[lk4 + 0][lrow] = wv.x; Ws[lk4 + 1][lrow] = wv.y;
    Ws[lk4 + 2][lrow] = wv.z; Ws[lk4 + 3][lrow] = wv.w;
    __syncthreads();
#pragma unroll
    for (int kk = 0; kk < 16; ++kk) {
      float a[4], bv[4];
#pragma unroll
      for (int i = 0; i < 4; ++i) a[i] = Xs[kk][(ty << 2) + i];
#pragma unroll
      for (int j = 0; j < 4; ++j) bv[j] = Ws[kk][(tx << 2) + j];
#pragma unroll
      for (int i = 0; i < 4; ++i)
#pragma unroll
        for (int j = 0; j < 4; ++j) acc[i][j] += a[i] * bv[j];
    }
    __syncthreads();
  }
#pragma unroll
  for (int i = 0; i < 4; ++i) {
    int rl = (ty << 2) + i;
#pragma unroll
    for (int j = 0; j < 4; ++j) {
      int c = col0 + (tx << 2) + j;
      pb[(size_t)(row0 + rl) * Dm + c] = acc[i][j];
    }
  }
}

// ---- x[n,:] += cw0*(y0 + b2[e0]) + cw1*(y1 + b2[e1]) ----
__global__ void k_moe_add(float* __restrict__ x, const float* __restrict__ pb,
                          const int* __restrict__ sof, const float* __restrict__ ecw,
                          const int* __restrict__ eidx, const float* __restrict__ b2)
{
  int n = blockIdx.x;
  int s0 = sof[2 * n], s1 = sof[2 * n + 1];
  float c0 = ecw[2 * n], c1 = ecw[2 * n + 1];
  const float* bb0 = b2 + (size_t)eidx[2 * n] * Dm;
  const float* bb1 = b2 + (size_t)eidx[2 * n + 1] * Dm;
  const float* p0 = pb + (size_t)s0 * Dm;
  const float* p1 = pb + (size_t)s1 * Dm;
  float* xr = x + (size_t)n * Dm;
  for (int d = threadIdx.x; d < Dm; d += 256)
    xr[d] += c0 * (p0[d] + bb0[d]) + c1 * (p1[d] + bb1[d]);
}

// =====================================================================
// host-side launch helpers
// =====================================================================
static void launch_nt(hipStream_t st,
                      const float* X, int ldx, long long bxb, long long bxh,
                      const float* W, int ldw, long long bwb, long long bwh,
                      const float* bias, const float* R, int rmod,
                      float* Y, int ldy, long long byb, long long byh,
                      int M, int N, int K, int nH, int nbat, int act, float scale)
{
  dim3 g((unsigned)((N + 63) >> 6), (unsigned)((M + 63) >> 6), (unsigned)nbat);
  k_gemm_nt<<<g, 256, 0, st>>>(X, ldx, bxb, bxh, W, ldw, bwb, bwh, bias, R, rmod,
                               Y, ldy, byb, byh, M, N, K, nH, act, scale);
}
static void launch_nn(hipStream_t st,
                      const float* X, int ldx, long long bxb, long long bxh,
                      const float* W, int ldw, long long bwb, long long bwh,
                      float* Y, int ldy, long long byb, long long byh,
                      int M, int N, int K, int nH, int nbat)
{
  dim3 g((unsigned)((N + 63) >> 6), (unsigned)((M + 63) >> 6), (unsigned)nbat);
  k_gemm_nn<<<g, 256, 0, st>>>(X, ldx, bxb, bxh, W, ldw, bwb, bwh,
                               Y, ldy, byb, byh, M, N, K, nH);
}

extern "C" void kernel_launch(void* const* d_in, const int* in_sizes, int n_in,
                              void* d_out, int out_size, void* d_ws, size_t ws_size,
                              hipStream_t stream)
{
  (void)in_sizes; (void)n_in; (void)out_size; (void)ws_size;
  const float* img        = (const float*)d_in[0];
  const int*   idx        = (const int*)  d_in[1];
  const float* wte        = (const float*)d_in[2];
  const float* wpe        = (const float*)d_in[3];
  const float* wpe_img    = (const float*)d_in[4];
  const float* img_proj_w = (const float*)d_in[5];
  const float* e_ln1_s = (const float*)d_in[6];
  const float* e_ln1_b = (const float*)d_in[7];
  const float* e_qkv_w = (const float*)d_in[8];
  const float* e_qkv_b = (const float*)d_in[9];
  const float* e_proj_w = (const float*)d_in[10];
  const float* e_proj_b = (const float*)d_in[11];
  const float* e_ln2_s = (const float*)d_in[12];
  const float* e_ln2_b = (const float*)d_in[13];
  const float* e_fc_w  = (const float*)d_in[14];
  const float* e_fc_b  = (const float*)d_in[15];
  const float* e_fc2_w = (const float*)d_in[16];
  const float* e_fc2_b = (const float*)d_in[17];
  const float* d_ln1_s = (const float*)d_in[18];
  const float* d_ln1_b = (const float*)d_in[19];
  const float* d_qkv_w = (const float*)d_in[20];
  const float* d_qkv_b = (const float*)d_in[21];
  const float* d_proj_w = (const float*)d_in[22];
  const float* d_proj_b = (const float*)d_in[23];
  const float* d_ln2_s = (const float*)d_in[24];
  const float* d_ln2_b = (const float*)d_in[25];
  const float* d_kv_w  = (const float*)d_in[26];
  const float* d_kv_b  = (const float*)d_in[27];
  const float* d_q_w   = (const float*)d_in[28];
  const float* d_q_b   = (const float*)d_in[29];
  const float* d_cproj_w = (const float*)d_in[30];
  const float* d_cproj_b = (const float*)d_in[31];
  const float* d_ln3_s = (const float*)d_in[32];
  const float* d_ln3_b = (const float*)d_in[33];
  const float* gate_w  = (const float*)d_in[34];
  const float* gate_b  = (const float*)d_in[35];
  const float* exp_w1  = (const float*)d_in[36];
  const float* exp_b1  = (const float*)d_in[37];
  const float* exp_w2  = (const float*)d_in[38];
  const float* exp_b2  = (const float*)d_in[39];
  const float* lnf_s   = (const float*)d_in[40];
  const float* lnf_b   = (const float*)d_in[41];
  float* out = (float*)d_out;

  float* ws = (float*)d_ws;
  size_t off = 0;
  auto alloc = [&](size_t n) { float* p = ws + off; off += (n + 63) & ~(size_t)63; return p; };
  float* x   = alloc((size_t)NTOK * Dm);
  float* xi  = alloc((size_t)NIMG * Dm);
  float* hb  = alloc((size_t)NTOK * Dm);
  float* qkv = alloc((size_t)NTOK * 3 * Dm);   // also encoder fc buffer [196,3072]
  float* kvb = alloc((size_t)NIMG * 2 * Dm);
  float* qb  = alloc((size_t)NTOK * Dm);
  float* att = alloc((size_t)NTOK * Dm);
  float* sc  = alloc((size_t)Bbatch * Hh * Tt * Tt);
  float* Hm  = alloc((size_t)SLOTS * FFf);
  float* pb  = alloc((size_t)SLOTS * Dm);
  float* ecw = alloc((size_t)2 * NTOK);
  int* eidx   = (int*)(ws + off);
  int* counts = eidx + 2 * NTOK;
  int* offs   = counts + Ee;
  int* cursor = offs + Ee + 1;
  int* te     = cursor + Ee;
  int* tr0    = te + MAXTILES;
  int* trn    = tr0 + MAXTILES;
  int* ntl    = trn + MAXTILES;
  int* stok   = ntl + 1;
  int* sof    = stok + SLOTS;

  const long long LL64 = 64;

  // ---- embeddings ----
  k_embed<<<NTOK, 256, 0, stream>>>(idx, wte, wpe, x);
  // xi = img @ img_proj_w^T + wpe_img (broadcast over batch via rmod=49)
  launch_nt(stream, img, IMGF, 0, 0, img_proj_w, IMGF, 0, 0, nullptr, wpe_img, TIi,
            xi, Dm, 0, 0, NIMG, Dm, IMGF, 1, 1, 0, 1.f);

  // ---- visual encoder ----
  for (int i = 0; i < Ll; ++i) {
    const float* qw  = e_qkv_w + (size_t)i * 3 * Dm * Dm;
    const float* qbv = e_qkv_b + (size_t)i * 3 * Dm;
    const float* pw  = e_proj_w + (size_t)i * Dm * Dm;
    const float* pbv = e_proj_b + (size_t)i * Dm;
    const float* fw  = e_fc_w + (size_t)i * FFf * Dm;
    const float* fbv = e_fc_b + (size_t)i * FFf;
    const float* f2w = e_fc2_w + (size_t)i * Dm * FFf;
    const float* f2b = e_fc2_b + (size_t)i * Dm;

    k_ln<<<NIMG, 256, 0, stream>>>(xi, e_ln1_s + i * Dm, e_ln1_b + i * Dm, hb);
    launch_nt(stream, hb, Dm, 0, 0, qw, Dm, 0, 0, qbv, nullptr, 1,
              qkv, 3 * Dm, 0, 0, NIMG, 3 * Dm, Dm, 1, 1, 0, 1.f);
    // scores[bh][q][k], ld 64
    launch_nt(stream, qkv, 3 * Dm, (long long)TIi * 3 * Dm, LL64,
              qkv + Dm, 3 * Dm, (long long)TIi * 3 * Dm, LL64, nullptr, nullptr, 1,
              sc, 64, (long long)Hh * TIi * 64, (long long)TIi * 64,
              TIi, TIi, HD, Hh, Bbatch * Hh, 0, 0.125f);
    k_softmax<<<dim3(TIi, Bbatch * Hh), 64, 0, stream>>>(sc, TIi, TIi, 64, 0);
    launch_nn(stream, sc, 64, (long long)Hh * TIi * 64, (long long)TIi * 64,
              qkv + 2 * Dm, 3 * Dm, (long long)TIi * 3 * Dm, LL64,
              att, Dm, (long long)TIi * Dm, LL64, TIi, HD, TIi, Hh, Bbatch * Hh);
    launch_nt(stream, att, Dm, 0, 0, pw, Dm, 0, 0, pbv, xi, NIMG,
              xi, Dm, 0, 0, NIMG, Dm, Dm, 1, 1, 0, 1.f);
    k_ln<<<NIMG, 256, 0, stream>>>(xi, e_ln2_s + i * Dm, e_ln2_b + i * Dm, hb);
    launch_nt(stream, hb, Dm, 0, 0, fw, Dm, 0, 0, fbv, nullptr, 1,
              qkv, FFf, 0, 0, NIMG, FFf, Dm, 1, 1, 1 /*gelu*/, 1.f);
    launch_nt(stream, qkv, FFf, 0, 0, f2w, FFf, 0, 0, f2b, xi, NIMG,
              xi, Dm, 0, 0, NIMG, Dm, FFf, 1, 1, 0, 1.f);
  }

  // ---- decoder ----
  for (int i = 0; i < Ll; ++i) {
    const float* qw   = d_qkv_w + (size_t)i * 3 * Dm * Dm;
    const float* qbv  = d_qkv_b + (size_t)i * 3 * Dm;
    const float* pw   = d_proj_w + (size_t)i * Dm * Dm;
    const float* pbv  = d_proj_b + (size_t)i * Dm;
    const float* kvw  = d_kv_w + (size_t)i * 2 * Dm * Dm;
    const float* kvbv = d_kv_b + (size_t)i * 2 * Dm;
    const float* dqw  = d_q_w + (size_t)i * Dm * Dm;
    const float* dqb  = d_q_b + (size_t)i * Dm;
    const float* cpw  = d_cproj_w + (size_t)i * Dm * Dm;
    const float* cpb  = d_cproj_b + (size_t)i * Dm;

    // -- causal self-attention --
    k_ln<<<NTOK, 256, 0, stream>>>(x, d_ln1_s + i * Dm, d_ln1_b + i * Dm, hb);
    launch_nt(stream, hb, Dm, 0, 0, qw, Dm, 0, 0, qbv, nullptr, 1,
              qkv, 3 * Dm, 0, 0, NTOK, 3 * Dm, Dm, 1, 1, 0, 1.f);
    launch_nt(stream, qkv, 3 * Dm, (long long)Tt * 3 * Dm, LL64,
              qkv + Dm, 3 * Dm, (long long)Tt * 3 * Dm, LL64, nullptr, nullptr, 1,
              sc, Tt, (long long)Hh * Tt * Tt, (long long)Tt * Tt,
              Tt, Tt, HD, Hh, Bbatch * Hh, 0, 0.125f);
    k_softmax<<<dim3(Tt, Bbatch * Hh), 64, 0, stream>>>(sc, Tt, Tt, Tt, 1);
    launch_nn(stream, sc, Tt, (long long)Hh * Tt * Tt, (long long)Tt * Tt,
              qkv + 2 * Dm, 3 * Dm, (long long)Tt * 3 * Dm, LL64,
              att, Dm, (long long)Tt * Dm, LL64, Tt, HD, Tt, Hh, Bbatch * Hh);
    launch_nt(stream, att, Dm, 0, 0, pw, Dm, 0, 0, pbv, x, NTOK,
              x, Dm, 0, 0, NTOK, Dm, Dm, 1, 1, 0, 1.f);

    // -- cross-attention --
    k_ln<<<NIMG, 256, 0, stream>>>(xi, d_ln2_s + i * Dm, d_ln2_b + i * Dm, hb);
    launch_nt(stream, hb, Dm, 0, 0, kvw, Dm, 0, 0, kvbv, nullptr, 1,
              kvb, 2 * Dm, 0, 0, NIMG, 2 * Dm, Dm, 1, 1, 0, 1.f);
    k_ln<<<NTOK, 256, 0, stream>>>(x, d_ln2_s + i * Dm, d_ln2_b + i * Dm, hb);
    launch_nt(stream, hb, Dm, 0, 0, dqw, Dm, 0, 0, dqb, nullptr, 1,
              qb, Dm, 0, 0, NTOK, Dm, Dm, 1, 1, 0, 1.f);
    launch_nt(stream, qb, Dm, (long long)Tt * Dm, LL64,
              kvb, 2 * Dm, (long long)TIi * 2 * Dm, LL64, nullptr, nullptr, 1,
              sc, 64, (long long)Hh * Tt * 64, (long long)Tt * 64,
              Tt, TIi, HD, Hh, Bbatch * Hh, 0, 0.125f);
    k_softmax<<<dim3(Tt, Bbatch * Hh), 64, 0, stream>>>(sc, Tt, TIi, 64, 0);
    launch_nn(stream, sc, 64, (long long)Hh * Tt * 64, (long long)Tt * 64,
              kvb + Dm, 2 * Dm, (long long)TIi * 2 * Dm, LL64,
              att, Dm, (long long)Tt * Dm, LL64, Tt, HD, TIi, Hh, Bbatch * Hh);
    launch_nt(stream, att, Dm, 0, 0, cpw, Dm, 0, 0, cpb, x, NTOK,
              x, Dm, 0, 0, NTOK, Dm, Dm, 1, 1, 0, 1.f);

    // -- MoE --
    k_ln<<<NTOK, 256, 0, stream>>>(x, d_ln3_s + i * Dm, d_ln3_b + i * Dm, hb);
    hipMemsetAsync(counts, 0, Ee * sizeof(int), stream);
    k_gate<<<NTOK, 64, 0, stream>>>(hb, gate_w + (size_t)i * Ee * Dm,
                                    gate_b + (size_t)i * Ee, eidx, ecw, counts);
    k_scan<<<1, 1, 0, stream>>>(counts, offs, cursor, te, tr0, trn, ntl);
    k_scatter<<<(2 * NTOK + 255) / 256, 256, 0, stream>>>(eidx, offs, cursor, stok, sof);
    k_moe_gemm1<<<dim3(FFf / 64, MAXTILES), 256, 0, stream>>>(
        hb, exp_w1 + (size_t)i * Ee * FFf * Dm, exp_b1 + (size_t)i * Ee * FFf,
        te, tr0, trn, ntl, stok, Hm);
    k_moe_gemm2<<<dim3(Dm / 64, MAXTILES), 256, 0, stream>>>(
        Hm, exp_w2 + (size_t)i * Ee * Dm * FFf, te, tr0, ntl, pb);
    k_moe_add<<<NTOK, 256, 0, stream>>>(x, pb, sof, ecw, eidx,
                                        exp_b2 + (size_t)i * Ee * Dm);
  }

  // ---- final LN + tied LM head ----
  k_ln<<<NTOK, 256, 0, stream>>>(x, lnf_s, lnf_b, hb);
  launch_nt(stream, hb, Dm, 0, 0, wte, Dm, 0, 0, nullptr, nullptr, 1,
            out, Vv, 0, 0, NTOK, Vv, Dm, 1, 1, 0, 1.f);
}